// Round 1
// baseline (1039.674 us; speedup 1.0000x reference)
//
#include <hip/hip_runtime.h>
#include <hip/hip_bf16.h>

typedef __attribute__((ext_vector_type(8))) short short8;
typedef __attribute__((ext_vector_type(8))) unsigned short ushort8;
typedef __attribute__((ext_vector_type(4))) unsigned short ushort4v;
typedef __attribute__((ext_vector_type(4))) float f32x4;

#define NTOK 5120
#define DDIM 256

__device__ __forceinline__ unsigned short f2bf(float f) {
  union { float f; unsigned int u; } x; x.f = f;
  unsigned int r = x.u + 0x7FFFu + ((x.u >> 16) & 1u);
  return (unsigned short)(r >> 16);
}

// ---------------- Kernel 1: depthwise conv Q,K + unfold -> token-major bf16 [b][5120][256]
__global__ __launch_bounds__(256) void qk_gen(
    const float* __restrict__ xin, const float* __restrict__ wq,
    const float* __restrict__ bq, const float* __restrict__ wk,
    const float* __restrict__ bk, unsigned short* __restrict__ qt,
    unsigned short* __restrict__ kt)
{
  const int ch = blockIdx.x;   // 0..63
  const int bt = blockIdx.y;   // 0..9
  const int b = bt / 5, tf = bt % 5;
  const int tid = threadIdx.x;
  const float* xp = xin + ((size_t)bt * 64 + ch) * 4096;
  float wqv[9], wkv[9];
  #pragma unroll
  for (int i = 0; i < 9; i++) { wqv[i] = wq[ch * 9 + i]; wkv[i] = wk[ch * 9 + i]; }
  const float bqv = bq[ch], bkv = bk[ch];

  #pragma unroll
  for (int p = 0; p < 4; p++) {
    int pid = tid + p * 256;         // patch id in frame (gy*32+gx)
    int gy = pid >> 5, gx = pid & 31;
    float v[4][4];
    #pragma unroll
    for (int r = 0; r < 4; r++) {
      int yy = 2 * gy - 1 + r;
      #pragma unroll
      for (int cc = 0; cc < 4; cc++) {
        int xx = 2 * gx - 1 + cc;
        bool ok = (yy >= 0) && (yy < 64) && (xx >= 0) && (xx < 64);
        v[r][cc] = ok ? xp[yy * 64 + xx] : 0.f;
      }
    }
    unsigned short qo[4], ko[4];
    #pragma unroll
    for (int py = 0; py < 2; py++)
      #pragma unroll
      for (int px = 0; px < 2; px++) {
        float aq = bqv, ak = bkv;
        #pragma unroll
        for (int dy = 0; dy < 3; dy++)
          #pragma unroll
          for (int dx = 0; dx < 3; dx++) {
            float xv = v[py + dy][px + dx];
            aq += wqv[dy * 3 + dx] * xv;
            ak += wkv[dy * 3 + dx] * xv;
          }
        qo[py * 2 + px] = f2bf(aq);
        ko[py * 2 + px] = f2bf(ak);
      }
    size_t base = ((size_t)(b * NTOK + tf * 1024 + pid)) * DDIM + ch * 4;
    ushort4v qv = { qo[0], qo[1], qo[2], qo[3] };
    ushort4v kv = { ko[0], ko[1], ko[2], ko[3] };
    *(ushort4v*)(qt + base) = qv;
    *(ushort4v*)(kt + base) = kv;
  }
}

// ---------------- Kernel 2: dense conv V + unfold -> d-major bf16 [b][256][5120]
__global__ __launch_bounds__(256) void v_gen(
    const float* __restrict__ xin, const float* __restrict__ wv,
    const float* __restrict__ bv, unsigned short* __restrict__ vt)
{
  const int coq = blockIdx.x;  // 0..15
  const int bt = blockIdx.y;   // 0..9
  const int b = bt / 5, tf = bt % 5;
  const int tid = threadIdx.x;
  const int wave = tid >> 6;
  const int lane = tid & 63;
  const int co = coq * 4 + wave;       // one out-channel per wave
  const int y0 = (lane >> 2) * 4;      // 4 output rows per thread
  const int x0 = (lane & 3) * 16;      // 16 output cols per thread

  float acc[4][16];
  #pragma unroll
  for (int a = 0; a < 4; a++)
    #pragma unroll
    for (int i = 0; i < 16; i++) acc[a][i] = 0.f;

  #pragma unroll 1
  for (int ci = 0; ci < 64; ++ci) {
    const float* wp = wv + ((size_t)co * 64 + ci) * 9;
    float w[9];
    #pragma unroll
    for (int i = 0; i < 9; i++) w[i] = wp[i];
    const float* xp = xin + ((size_t)bt * 64 + ci) * 4096;
    #pragma unroll
    for (int ry = 0; ry < 6; ++ry) {
      int row = y0 + ry - 1;
      bool rok = (row >= 0) && (row < 64);
      float vr[24];
      #pragma unroll
      for (int bb = 0; bb < 6; bb++) {
        int xs = x0 + bb * 4 - 4;
        f32x4 t = { 0.f, 0.f, 0.f, 0.f };
        if (rok && xs >= 0 && xs < 64) t = *(const f32x4*)(xp + row * 64 + xs);
        vr[bb * 4 + 0] = t[0]; vr[bb * 4 + 1] = t[1];
        vr[bb * 4 + 2] = t[2]; vr[bb * 4 + 3] = t[3];
      }
      #pragma unroll
      for (int oy = 0; oy < 4; oy++) {
        int dy = ry - oy;
        if (dy >= 0 && dy <= 2) {
          float w0 = w[dy * 3 + 0], w1 = w[dy * 3 + 1], w2 = w[dy * 3 + 2];
          #pragma unroll
          for (int i = 0; i < 16; i++)
            acc[oy][i] += w0 * vr[i + 3] + w1 * vr[i + 4] + w2 * vr[i + 5];
        }
      }
    }
  }
  const float vb = bv[co];
  #pragma unroll
  for (int oy = 0; oy < 4; oy++) {
    int y = y0 + oy;
    int py = y & 1, gy = y >> 1;
    ushort8 w0, w1;
    #pragma unroll
    for (int i = 0; i < 8; i++) {
      w0[i] = f2bf(acc[oy][2 * i + 0] + vb);   // px=0
      w1[i] = f2bf(acc[oy][2 * i + 1] + vb);   // px=1
    }
    size_t base0 = ((size_t)(b * DDIM + co * 4 + py * 2)) * NTOK + tf * 1024 + gy * 32 + (x0 >> 1);
    *(ushort8*)(vt + base0) = w0;
    *(ushort8*)(vt + base0 + NTOK) = w1;
  }
}

// ---------------- Kernel 3: flash attention (bf16 MFMA), writes folded feat f32 [bt][c][64][64]
__global__ __launch_bounds__(256) void attn_kernel(
    const unsigned short* __restrict__ qt, const unsigned short* __restrict__ kt,
    const unsigned short* __restrict__ vt, float* __restrict__ feat)
{
  const int b = blockIdx.y;
  const int i0 = blockIdx.x * 64;
  const int tid = threadIdx.x;
  const int w = tid >> 6, lane = tid & 63;
  const int g = lane >> 4, c = lane & 15;

  __shared__ __align__(16) unsigned short lds_k[64 * 256];   // [j][d], swizzled
  __shared__ __align__(16) unsigned short lds_v[256 * 64];   // [d][j], swizzled
  __shared__ __align__(16) unsigned short lds_p[4 * 16 * 64];// per-wave P [i][j], swizzled

  // Q fragments held in registers: rows i0 + w*16 + c, k = kb*32 + 8g + e
  short8 qf[8];
  {
    const unsigned short* qr = qt + ((size_t)(b * NTOK + i0 + w * 16 + c)) * DDIM + g * 8;
    #pragma unroll
    for (int kb = 0; kb < 8; kb++) qf[kb] = *(const short8*)(qr + kb * 32);
  }
  f32x4 o[16];
  #pragma unroll
  for (int i = 0; i < 16; i++) o[i] = (f32x4){ 0.f, 0.f, 0.f, 0.f };
  float m[4] = { -1e30f, -1e30f, -1e30f, -1e30f };
  float l[4] = { 0.f, 0.f, 0.f, 0.f };

  const int sr = tid >> 5, sc = tid & 31;   // K staging: row base / 16B slot
  const int vdr = tid >> 3, vcc = tid & 7;  // V staging

  for (int j0 = 0; j0 < NTOK; j0 += 64) {
    // ---- stage K tile [64][256] (swizzle: slot ^= row&7)
    #pragma unroll
    for (int p = 0; p < 8; p++) {
      int row = sr + p * 8;
      short8 kv = *(const short8*)(kt + ((size_t)(b * NTOK + j0 + row)) * DDIM + sc * 8);
      *(short8*)((char*)lds_k + row * 512 + ((sc ^ (row & 7)) * 16)) = kv;
    }
    // ---- stage V tile [256][64]
    #pragma unroll
    for (int p = 0; p < 8; p++) {
      int dd = vdr + p * 32;
      short8 vv = *(const short8*)(vt + ((size_t)(b * DDIM + dd)) * NTOK + j0 + vcc * 8);
      *(short8*)((char*)lds_v + dd * 128 + ((vcc ^ (dd & 7)) * 16)) = vv;
    }
    __syncthreads();

    // ---- S = Q * K^T  (16 rows x 64 cols per wave)
    f32x4 s[4];
    #pragma unroll
    for (int js = 0; js < 4; js++) {
      s[js] = (f32x4){ 0.f, 0.f, 0.f, 0.f };
      int row = js * 16 + c;
      int sw = row & 7;
      #pragma unroll
      for (int kb = 0; kb < 8; kb++) {
        short8 kf = *(const short8*)((char*)lds_k + row * 512 + (((kb * 4 + g) ^ sw) * 16));
        s[js] = __builtin_amdgcn_mfma_f32_16x16x32_bf16(qf[kb], kf, s[js], 0, 0, 0);
      }
    }
    // ---- online softmax (rows r=0..3 of this lane; reduce over 16 col-lanes)
    float pv[4][4];
    float alpha[4];
    #pragma unroll
    for (int r = 0; r < 4; r++) {
      float mx = fmaxf(fmaxf(s[0][r], s[1][r]), fmaxf(s[2][r], s[3][r])) * 0.0625f;
      #pragma unroll
      for (int off = 1; off < 16; off <<= 1) mx = fmaxf(mx, __shfl_xor(mx, off));
      float mn = fmaxf(m[r], mx);
      alpha[r] = __expf(m[r] - mn);
      float sum = 0.f;
      #pragma unroll
      for (int js = 0; js < 4; js++) {
        float pe = __expf(s[js][r] * 0.0625f - mn);
        pv[js][r] = pe; sum += pe;
      }
      #pragma unroll
      for (int off = 1; off < 16; off <<= 1) sum += __shfl_xor(sum, off);
      l[r] = l[r] * alpha[r] + sum;
      m[r] = mn;
    }
    {
      f32x4 av = { alpha[0], alpha[1], alpha[2], alpha[3] };
      #pragma unroll
      for (int ds = 0; ds < 16; ds++) o[ds] *= av;
    }
    // ---- P (D-layout) -> per-wave LDS, bf16, swizzled
    char* pb = (char*)lds_p + w * 2048;
    #pragma unroll
    for (int js = 0; js < 4; js++)
      #pragma unroll
      for (int r = 0; r < 4; r++) {
        int row = 4 * g + r;
        int slot = (js * 2 + (c >> 3)) ^ (row & 7);
        *(unsigned short*)(pb + row * 128 + slot * 16 + (c & 7) * 2) = f2bf(pv[js][r]);
      }
    short8 pf[2];
    #pragma unroll
    for (int k2 = 0; k2 < 2; k2++)
      pf[k2] = *(short8*)(pb + c * 128 + (((k2 * 4 + g) ^ (c & 7)) * 16));
    // ---- O += P * V
    #pragma unroll
    for (int ds = 0; ds < 16; ds++) {
      int vrow = ds * 16 + c;
      int sw = c & 7;
      #pragma unroll
      for (int k2 = 0; k2 < 2; k2++) {
        short8 vf = *(const short8*)((char*)lds_v + vrow * 128 + (((k2 * 4 + g) ^ sw) * 16));
        o[ds] = __builtin_amdgcn_mfma_f32_16x16x32_bf16(pf[k2], vf, o[ds], 0, 0, 0);
      }
    }
    __syncthreads();
  }
  // ---- epilogue: normalize, fold directly into feat[bt][ch][y][x] (f32)
  f32x4 lv = { 1.f / l[0], 1.f / l[1], 1.f / l[2], 1.f / l[3] };
  #pragma unroll
  for (int ds = 0; ds < 16; ds++) {
    f32x4 ov = o[ds] * lv;
    int dd = ds * 16 + c;
    int ch = dd >> 2, py = (dd >> 1) & 1, px = dd & 1;
    #pragma unroll
    for (int r = 0; r < 4; r++) {
      int it = i0 + w * 16 + 4 * g + r;
      int tf = it >> 10, jn = it & 1023;
      int gy = jn >> 5, gx = jn & 31;
      size_t addr = ((size_t)((b * 5 + tf) * 64 + ch)) * 4096 + (2 * gy + py) * 64 + (2 * gx + px);
      feat[addr] = ov[r];
    }
  }
}

// ---------------- Kernel 4: dense conv on feat + bias + residual -> out (f32)
__global__ __launch_bounds__(256) void conv_out(
    const float* __restrict__ feat, const float* __restrict__ wc,
    const float* __restrict__ bc, const float* __restrict__ xin,
    float* __restrict__ out)
{
  const int coq = blockIdx.x;
  const int bt = blockIdx.y;
  const int tid = threadIdx.x;
  const int wave = tid >> 6;
  const int lane = tid & 63;
  const int co = coq * 4 + wave;
  const int y0 = (lane >> 2) * 4;
  const int x0 = (lane & 3) * 16;

  float acc[4][16];
  #pragma unroll
  for (int a = 0; a < 4; a++)
    #pragma unroll
    for (int i = 0; i < 16; i++) acc[a][i] = 0.f;

  #pragma unroll 1
  for (int ci = 0; ci < 64; ++ci) {
    const float* wp = wc + ((size_t)co * 64 + ci) * 9;
    float w[9];
    #pragma unroll
    for (int i = 0; i < 9; i++) w[i] = wp[i];
    const float* fp = feat + ((size_t)bt * 64 + ci) * 4096;
    #pragma unroll
    for (int ry = 0; ry < 6; ++ry) {
      int row = y0 + ry - 1;
      bool rok = (row >= 0) && (row < 64);
      float vr[24];
      #pragma unroll
      for (int bb = 0; bb < 6; bb++) {
        int xs = x0 + bb * 4 - 4;
        f32x4 t = { 0.f, 0.f, 0.f, 0.f };
        if (rok && xs >= 0 && xs < 64) t = *(const f32x4*)(fp + row * 64 + xs);
        vr[bb * 4 + 0] = t[0]; vr[bb * 4 + 1] = t[1];
        vr[bb * 4 + 2] = t[2]; vr[bb * 4 + 3] = t[3];
      }
      #pragma unroll
      for (int oy = 0; oy < 4; oy++) {
        int dy = ry - oy;
        if (dy >= 0 && dy <= 2) {
          float w0 = w[dy * 3 + 0], w1 = w[dy * 3 + 1], w2 = w[dy * 3 + 2];
          #pragma unroll
          for (int i = 0; i < 16; i++)
            acc[oy][i] += w0 * vr[i + 3] + w1 * vr[i + 4] + w2 * vr[i + 5];
        }
      }
    }
  }
  const float bcv = bc[co];
  const size_t pb = ((size_t)bt * 64 + co) * 4096;
  #pragma unroll
  for (int oy = 0; oy < 4; oy++) {
    size_t rbase = pb + (size_t)(y0 + oy) * 64 + x0;
    #pragma unroll
    for (int q = 0; q < 4; q++) {
      f32x4 xr = *(const f32x4*)(xin + rbase + q * 4);
      f32x4 ov;
      ov[0] = acc[oy][q * 4 + 0] + bcv + xr[0];
      ov[1] = acc[oy][q * 4 + 1] + bcv + xr[1];
      ov[2] = acc[oy][q * 4 + 2] + bcv + xr[2];
      ov[3] = acc[oy][q * 4 + 3] + bcv + xr[3];
      *(f32x4*)(out + rbase + q * 4) = ov;
    }
  }
}

extern "C" void kernel_launch(void* const* d_in, const int* in_sizes, int n_in,
                              void* d_out, int out_size, void* d_ws, size_t ws_size,
                              hipStream_t stream) {
  const float* x  = (const float*)d_in[0];
  const float* wq = (const float*)d_in[1];
  const float* bq = (const float*)d_in[2];
  const float* wk = (const float*)d_in[3];
  const float* bk = (const float*)d_in[4];
  const float* wv = (const float*)d_in[5];
  const float* bv = (const float*)d_in[6];
  const float* wc = (const float*)d_in[7];
  const float* bc = (const float*)d_in[8];
  float* out = (float*)d_out;

  char* ws = (char*)d_ws;
  unsigned short* qt = (unsigned short*)(ws);                 // 5,242,880 B
  unsigned short* kt = (unsigned short*)(ws + 5242880);       // 5,242,880 B
  unsigned short* vt = (unsigned short*)(ws + 10485760);      // 5,242,880 B
  float*          ft = (float*)(ws + 15728640);               // 10,485,760 B  (total ~25 MB)

  qk_gen   <<<dim3(64, 10), 256, 0, stream>>>(x, wq, bq, wk, bk, qt, kt);
  v_gen    <<<dim3(16, 10), 256, 0, stream>>>(x, wv, bv, vt);
  attn_kernel<<<dim3(80, 2), 256, 0, stream>>>(qt, kt, vt, ft);
  conv_out <<<dim3(16, 10), 256, 0, stream>>>(ft, wc, bc, x, out);
}

// Round 2
// 1006.344 us; speedup vs baseline: 1.0331x; 1.0331x over previous
//
#include <hip/hip_runtime.h>
#include <hip/hip_bf16.h>

typedef __attribute__((ext_vector_type(8))) short short8;
typedef __attribute__((ext_vector_type(8))) unsigned short ushort8;
typedef __attribute__((ext_vector_type(4))) unsigned short ushort4v;
typedef __attribute__((ext_vector_type(4))) float f32x4;

#define NTOK 5120
#define DDIM 256

__device__ __forceinline__ unsigned short f2bf(float f) {
  union { float f; unsigned int u; } x; x.f = f;
  unsigned int r = x.u + 0x7FFFu + ((x.u >> 16) & 1u);
  return (unsigned short)(r >> 16);
}

// ---------------- Kernel 1: depthwise conv Q,K + unfold -> token-major bf16 [b][5120][256]
__global__ __launch_bounds__(256) void qk_gen(
    const float* __restrict__ xin, const float* __restrict__ wq,
    const float* __restrict__ bq, const float* __restrict__ wk,
    const float* __restrict__ bk, unsigned short* __restrict__ qt,
    unsigned short* __restrict__ kt)
{
  const int ch = blockIdx.x;   // 0..63
  const int bt = blockIdx.y;   // 0..9
  const int b = bt / 5, tf = bt % 5;
  const int tid = threadIdx.x;
  const float* xp = xin + ((size_t)bt * 64 + ch) * 4096;
  float wqv[9], wkv[9];
  #pragma unroll
  for (int i = 0; i < 9; i++) { wqv[i] = wq[ch * 9 + i]; wkv[i] = wk[ch * 9 + i]; }
  const float bqv = bq[ch], bkv = bk[ch];

  #pragma unroll
  for (int p = 0; p < 4; p++) {
    int pid = tid + p * 256;         // patch id in frame (gy*32+gx)
    int gy = pid >> 5, gx = pid & 31;
    float v[4][4];
    #pragma unroll
    for (int r = 0; r < 4; r++) {
      int yy = 2 * gy - 1 + r;
      #pragma unroll
      for (int cc = 0; cc < 4; cc++) {
        int xx = 2 * gx - 1 + cc;
        bool ok = (yy >= 0) && (yy < 64) && (xx >= 0) && (xx < 64);
        v[r][cc] = ok ? xp[yy * 64 + xx] : 0.f;
      }
    }
    unsigned short qo[4], ko[4];
    #pragma unroll
    for (int py = 0; py < 2; py++)
      #pragma unroll
      for (int px = 0; px < 2; px++) {
        float aq = bqv, ak = bkv;
        #pragma unroll
        for (int dy = 0; dy < 3; dy++)
          #pragma unroll
          for (int dx = 0; dx < 3; dx++) {
            float xv = v[py + dy][px + dx];
            aq += wqv[dy * 3 + dx] * xv;
            ak += wkv[dy * 3 + dx] * xv;
          }
        qo[py * 2 + px] = f2bf(aq);
        ko[py * 2 + px] = f2bf(ak);
      }
    size_t base = ((size_t)(b * NTOK + tf * 1024 + pid)) * DDIM + ch * 4;
    ushort4v qv = { qo[0], qo[1], qo[2], qo[3] };
    ushort4v kv = { ko[0], ko[1], ko[2], ko[3] };
    *(ushort4v*)(qt + base) = qv;
    *(ushort4v*)(kt + base) = kv;
  }
}

// ---------------- Kernel 2: dense 3x3 conv, HALF the input channels -> f32 partial (no bias)
// part layout: [cih][bt][co][64][64]
__global__ __launch_bounds__(256) void conv_part(
    const float* __restrict__ src, const float* __restrict__ wmat,
    float* __restrict__ part)
{
  const int coq = blockIdx.x;  // 0..15
  const int cih = blockIdx.y;  // 0..1 (ci half)
  const int bt = blockIdx.z;   // 0..9
  const int tid = threadIdx.x;
  const int wave = tid >> 6;
  const int lane = tid & 63;
  const int co = coq * 4 + wave;       // one out-channel per wave
  const int y0 = (lane >> 2) * 4;      // 4 output rows per thread
  const int x0 = (lane & 3) * 16;      // 16 output cols per thread

  float acc[4][16];
  #pragma unroll
  for (int a = 0; a < 4; a++)
    #pragma unroll
    for (int i = 0; i < 16; i++) acc[a][i] = 0.f;

  #pragma unroll 1
  for (int cl = 0; cl < 32; ++cl) {
    const int ci = cih * 32 + cl;
    const float* wp = wmat + ((size_t)co * 64 + ci) * 9;
    float w[9];
    #pragma unroll
    for (int i = 0; i < 9; i++) w[i] = wp[i];
    const float* xp = src + ((size_t)bt * 64 + ci) * 4096;
    #pragma unroll
    for (int ry = 0; ry < 6; ++ry) {
      int row = y0 + ry - 1;
      bool rok = (row >= 0) && (row < 64);
      float vr[24];
      #pragma unroll
      for (int bb = 0; bb < 6; bb++) {
        int xs = x0 + bb * 4 - 4;
        f32x4 t = { 0.f, 0.f, 0.f, 0.f };
        if (rok && xs >= 0 && xs < 64) t = *(const f32x4*)(xp + row * 64 + xs);
        vr[bb * 4 + 0] = t[0]; vr[bb * 4 + 1] = t[1];
        vr[bb * 4 + 2] = t[2]; vr[bb * 4 + 3] = t[3];
      }
      #pragma unroll
      for (int oy = 0; oy < 4; oy++) {
        int dy = ry - oy;
        if (dy >= 0 && dy <= 2) {
          float w0 = w[dy * 3 + 0], w1 = w[dy * 3 + 1], w2 = w[dy * 3 + 2];
          #pragma unroll
          for (int i = 0; i < 16; i++)
            acc[oy][i] += w0 * vr[i + 3] + w1 * vr[i + 4] + w2 * vr[i + 5];
        }
      }
    }
  }
  float* pp = part + (((size_t)cih * 10 + bt) * 64 + co) * 4096;
  #pragma unroll
  for (int oy = 0; oy < 4; oy++) {
    size_t rbase = (size_t)(y0 + oy) * 64 + x0;
    #pragma unroll
    for (int q = 0; q < 4; q++) {
      f32x4 ov = { acc[oy][q*4+0], acc[oy][q*4+1], acc[oy][q*4+2], acc[oy][q*4+3] };
      *(f32x4*)(pp + rbase + q * 4) = ov;
    }
  }
}

// ---------------- V combine: sum 2 partials + bias -> bf16 tokens d-major [b][256][5120]
__global__ __launch_bounds__(256) void v_combine(
    const float* __restrict__ part, const float* __restrict__ bv,
    unsigned short* __restrict__ vt)
{
  const int co = blockIdx.x;   // 0..63
  const int bt = blockIdx.y;   // 0..9
  const int b = bt / 5, tf = bt % 5;
  const int t = threadIdx.x;
  const int y = t >> 2, xq = (t & 3) * 16;
  const float vb = bv[co];
  const float* p0 = part + (((size_t)0 * 10 + bt) * 64 + co) * 4096 + y * 64 + xq;
  const float* p1 = part + (((size_t)1 * 10 + bt) * 64 + co) * 4096 + y * 64 + xq;
  float val[16];
  #pragma unroll
  for (int q = 0; q < 4; q++) {
    f32x4 a = *(const f32x4*)(p0 + q * 4);
    f32x4 bq4 = *(const f32x4*)(p1 + q * 4);
    val[q*4+0] = a[0] + bq4[0] + vb; val[q*4+1] = a[1] + bq4[1] + vb;
    val[q*4+2] = a[2] + bq4[2] + vb; val[q*4+3] = a[3] + bq4[3] + vb;
  }
  int py = y & 1, gy = y >> 1;
  ushort8 w0, w1;
  #pragma unroll
  for (int i = 0; i < 8; i++) {
    w0[i] = f2bf(val[2 * i + 0]);   // px=0
    w1[i] = f2bf(val[2 * i + 1]);   // px=1
  }
  size_t base0 = ((size_t)(b * DDIM + co * 4 + py * 2)) * NTOK + tf * 1024 + gy * 32 + (xq >> 1);
  *(ushort8*)(vt + base0) = w0;
  *(ushort8*)(vt + base0 + NTOK) = w1;
}

// ---------------- Kernel 3: flash attention partials (j-split), writes unnormalized o + (m,l)
__global__ __launch_bounds__(256) void attn_kernel(
    const unsigned short* __restrict__ qt, const unsigned short* __restrict__ kt,
    const unsigned short* __restrict__ vt, float* __restrict__ po,
    float* __restrict__ pm, float* __restrict__ pl)
{
  const int b = blockIdx.z;
  const int jc = blockIdx.y;          // 0..3 j-chunk
  const int i0 = blockIdx.x * 64;
  const int tid = threadIdx.x;
  const int w = tid >> 6, lane = tid & 63;
  const int g = lane >> 4, c = lane & 15;

  __shared__ __align__(16) unsigned short lds_k[64 * 256];   // [j][d], swizzled
  __shared__ __align__(16) unsigned short lds_v[256 * 64];   // [d][j], swizzled
  __shared__ __align__(16) unsigned short lds_p[4 * 16 * 64];// per-wave P [i][j], swizzled

  short8 qf[8];
  {
    const unsigned short* qr = qt + ((size_t)(b * NTOK + i0 + w * 16 + c)) * DDIM + g * 8;
    #pragma unroll
    for (int kb = 0; kb < 8; kb++) qf[kb] = *(const short8*)(qr + kb * 32);
  }
  f32x4 o[16];
  #pragma unroll
  for (int i = 0; i < 16; i++) o[i] = (f32x4){ 0.f, 0.f, 0.f, 0.f };
  float m[4] = { -1e30f, -1e30f, -1e30f, -1e30f };
  float l[4] = { 0.f, 0.f, 0.f, 0.f };

  const int sr = tid >> 5, sc = tid & 31;
  const int vdr = tid >> 3, vcc = tid & 7;

  const int jbeg = jc * 1280;
  for (int j0 = jbeg; j0 < jbeg + 1280; j0 += 64) {
    #pragma unroll
    for (int p = 0; p < 8; p++) {
      int row = sr + p * 8;
      short8 kv = *(const short8*)(kt + ((size_t)(b * NTOK + j0 + row)) * DDIM + sc * 8);
      *(short8*)((char*)lds_k + row * 512 + ((sc ^ (row & 7)) * 16)) = kv;
    }
    #pragma unroll
    for (int p = 0; p < 8; p++) {
      int dd = vdr + p * 32;
      short8 vv = *(const short8*)(vt + ((size_t)(b * DDIM + dd)) * NTOK + j0 + vcc * 8);
      *(short8*)((char*)lds_v + dd * 128 + ((vcc ^ (dd & 7)) * 16)) = vv;
    }
    __syncthreads();

    f32x4 s[4];
    #pragma unroll
    for (int js = 0; js < 4; js++) {
      s[js] = (f32x4){ 0.f, 0.f, 0.f, 0.f };
      int row = js * 16 + c;
      int sw = row & 7;
      #pragma unroll
      for (int kb = 0; kb < 8; kb++) {
        short8 kf = *(const short8*)((char*)lds_k + row * 512 + (((kb * 4 + g) ^ sw) * 16));
        s[js] = __builtin_amdgcn_mfma_f32_16x16x32_bf16(qf[kb], kf, s[js], 0, 0, 0);
      }
    }
    float pv[4][4];
    float alpha[4];
    #pragma unroll
    for (int r = 0; r < 4; r++) {
      float mx = fmaxf(fmaxf(s[0][r], s[1][r]), fmaxf(s[2][r], s[3][r])) * 0.0625f;
      #pragma unroll
      for (int off = 1; off < 16; off <<= 1) mx = fmaxf(mx, __shfl_xor(mx, off));
      float mn = fmaxf(m[r], mx);
      alpha[r] = __expf(m[r] - mn);
      float sum = 0.f;
      #pragma unroll
      for (int js = 0; js < 4; js++) {
        float pe = __expf(s[js][r] * 0.0625f - mn);
        pv[js][r] = pe; sum += pe;
      }
      #pragma unroll
      for (int off = 1; off < 16; off <<= 1) sum += __shfl_xor(sum, off);
      l[r] = l[r] * alpha[r] + sum;
      m[r] = mn;
    }
    {
      f32x4 av = { alpha[0], alpha[1], alpha[2], alpha[3] };
      #pragma unroll
      for (int ds = 0; ds < 16; ds++) o[ds] *= av;
    }
    char* pb = (char*)lds_p + w * 2048;
    #pragma unroll
    for (int js = 0; js < 4; js++)
      #pragma unroll
      for (int r = 0; r < 4; r++) {
        int row = 4 * g + r;
        int slot = (js * 2 + (c >> 3)) ^ (row & 7);
        *(unsigned short*)(pb + row * 128 + slot * 16 + (c & 7) * 2) = f2bf(pv[js][r]);
      }
    short8 pf[2];
    #pragma unroll
    for (int k2 = 0; k2 < 2; k2++)
      pf[k2] = *(short8*)(pb + c * 128 + (((k2 * 4 + g) ^ (c & 7)) * 16));
    #pragma unroll
    for (int ds = 0; ds < 16; ds++) {
      int vrow = ds * 16 + c;
      int sw = c & 7;
      #pragma unroll
      for (int k2 = 0; k2 < 2; k2++) {
        short8 vf = *(const short8*)((char*)lds_v + vrow * 128 + (((k2 * 4 + g) ^ sw) * 16));
        o[ds] = __builtin_amdgcn_mfma_f32_16x16x32_bf16(pf[k2], vf, o[ds], 0, 0, 0);
      }
    }
    __syncthreads();
  }
  // ---- epilogue: store UNNORMALIZED partials
  const size_t rbase = ((size_t)(b * 4 + jc)) * NTOK + i0 + w * 16;
  #pragma unroll
  for (int ds = 0; ds < 16; ds++) {
    #pragma unroll
    for (int r = 0; r < 4; r++) {
      po[(rbase + 4 * g + r) * DDIM + ds * 16 + c] = o[ds][r];
    }
  }
  if (c == 0) {
    #pragma unroll
    for (int r = 0; r < 4; r++) {
      pm[rbase + 4 * g + r] = m[r];
      pl[rbase + 4 * g + r] = l[r];
    }
  }
}

// ---------------- attn combine: merge 4 j-chunk partials, fold into feat f32 [bt][c][64][64]
__global__ __launch_bounds__(256) void attn_combine(
    const float* __restrict__ po, const float* __restrict__ pm,
    const float* __restrict__ pl, float* __restrict__ feat)
{
  const int b = blockIdx.y;
  const int i0 = blockIdx.x * 64;
  const int t = threadIdx.x;
  const int row = t >> 2, dq = (t & 3) * 64;
  const int i = i0 + row;

  float mj[4], lj[4];
  #pragma unroll
  for (int jc = 0; jc < 4; jc++) {
    mj[jc] = pm[((size_t)(b * 4 + jc)) * NTOK + i];
    lj[jc] = pl[((size_t)(b * 4 + jc)) * NTOK + i];
  }
  float M = fmaxf(fmaxf(mj[0], mj[1]), fmaxf(mj[2], mj[3]));
  float wjc[4], L = 0.f;
  #pragma unroll
  for (int jc = 0; jc < 4; jc++) { wjc[jc] = __expf(mj[jc] - M); L += lj[jc] * wjc[jc]; }
  const float inv = 1.f / L;

  const int tf = i >> 10, jn = i & 1023;
  const int gy = jn >> 5, gx = jn & 31;
  const size_t fb = ((size_t)((b * 5 + tf) * 64)) * 4096 + (2 * gy) * 64 + 2 * gx;
  #pragma unroll
  for (int q = 0; q < 16; q++) {
    f32x4 acc = { 0.f, 0.f, 0.f, 0.f };
    #pragma unroll
    for (int jc = 0; jc < 4; jc++) {
      f32x4 v = *(const f32x4*)(po + (((size_t)(b * 4 + jc)) * NTOK + i) * DDIM + dq + q * 4);
      acc += v * wjc[jc];
    }
    acc *= inv;
    int ch = (dq + q * 4) >> 2;
    size_t base = fb + (size_t)ch * 4096;
    feat[base] = acc[0]; feat[base + 1] = acc[1];
    feat[base + 64] = acc[2]; feat[base + 65] = acc[3];
  }
}

// ---------------- out combine: sum 2 partials + bias + residual -> out (f32)
__global__ __launch_bounds__(256) void out_combine(
    const float* __restrict__ part, const float* __restrict__ bc,
    const float* __restrict__ xin, float* __restrict__ out)
{
  const int co = blockIdx.x;   // 0..63
  const int bt = blockIdx.y;   // 0..9
  const int t = threadIdx.x;
  const int y = t >> 2, xq = (t & 3) * 16;
  const float bcv = bc[co];
  const size_t obase = ((size_t)bt * 64 + co) * 4096 + y * 64 + xq;
  const float* p0 = part + (((size_t)0 * 10 + bt) * 64 + co) * 4096 + y * 64 + xq;
  const float* p1 = part + (((size_t)1 * 10 + bt) * 64 + co) * 4096 + y * 64 + xq;
  #pragma unroll
  for (int q = 0; q < 4; q++) {
    f32x4 a = *(const f32x4*)(p0 + q * 4);
    f32x4 bb = *(const f32x4*)(p1 + q * 4);
    f32x4 xr = *(const f32x4*)(xin + obase + q * 4);
    f32x4 ov;
    ov[0] = a[0] + bb[0] + bcv + xr[0];
    ov[1] = a[1] + bb[1] + bcv + xr[1];
    ov[2] = a[2] + bb[2] + bcv + xr[2];
    ov[3] = a[3] + bb[3] + bcv + xr[3];
    *(f32x4*)(out + obase + q * 4) = ov;
  }
}

extern "C" void kernel_launch(void* const* d_in, const int* in_sizes, int n_in,
                              void* d_out, int out_size, void* d_ws, size_t ws_size,
                              hipStream_t stream) {
  const float* x  = (const float*)d_in[0];
  const float* wq = (const float*)d_in[1];
  const float* bq = (const float*)d_in[2];
  const float* wk = (const float*)d_in[3];
  const float* bk = (const float*)d_in[4];
  const float* wv = (const float*)d_in[5];
  const float* bv = (const float*)d_in[6];
  const float* wc = (const float*)d_in[7];
  const float* bc = (const float*)d_in[8];
  float* out = (float*)d_out;

  char* ws = (char*)d_ws;
  unsigned short* qt = (unsigned short*)(ws);                 //  5,242,880 B
  unsigned short* kt = (unsigned short*)(ws + 5242880);       //  5,242,880 B
  unsigned short* vt = (unsigned short*)(ws + 10485760);      //  5,242,880 B
  float*          ft = (float*)(ws + 15728640);               // 10,485,760 B
  float*          big = (float*)(ws + 26214400);              // 41,943,040 B (conv partials / attn po)
  float*          pm = (float*)(ws + 68157440);               //    163,840 B
  float*          pl = (float*)(ws + 68321280);               //    163,840 B
  // total ~68.5 MB

  qk_gen      <<<dim3(64, 10), 256, 0, stream>>>(x, wq, bq, wk, bk, qt, kt);
  conv_part   <<<dim3(16, 2, 10), 256, 0, stream>>>(x, wv, big);
  v_combine   <<<dim3(64, 10), 256, 0, stream>>>(big, bv, vt);
  attn_kernel <<<dim3(80, 4, 2), 256, 0, stream>>>(qt, kt, vt, big, pm, pl);
  attn_combine<<<dim3(80, 2), 256, 0, stream>>>(big, pm, pl, ft);
  conv_part   <<<dim3(16, 2, 10), 256, 0, stream>>>(ft, wc, big);
  out_combine <<<dim3(64, 10), 256, 0, stream>>>(big, bc, x, out);
}

// Round 3
// 583.664 us; speedup vs baseline: 1.7813x; 1.7242x over previous
//
#include <hip/hip_runtime.h>
#include <hip/hip_bf16.h>

typedef __attribute__((ext_vector_type(8))) short short8;
typedef __attribute__((ext_vector_type(8))) unsigned short ushort8;
typedef __attribute__((ext_vector_type(4))) unsigned short ushort4v;
typedef __attribute__((ext_vector_type(4))) float f32x4;

#define NTOK 5120
#define DDIM 256

__device__ __forceinline__ unsigned short f2bf(float f) {
  union { float f; unsigned int u; } x; x.f = f;
  unsigned int r = x.u + 0x7FFFu + ((x.u >> 16) & 1u);
  return (unsigned short)(r >> 16);
}

// ---------------- Kernel 1: depthwise conv Q,K + unfold -> token-major bf16 [b][5120][256]
__global__ __launch_bounds__(256) void qk_gen(
    const float* __restrict__ xin, const float* __restrict__ wq,
    const float* __restrict__ bq, const float* __restrict__ wk,
    const float* __restrict__ bk, unsigned short* __restrict__ qt,
    unsigned short* __restrict__ kt)
{
  const int ch = blockIdx.x;   // 0..63
  const int bt = blockIdx.y;   // 0..9
  const int b = bt / 5, tf = bt % 5;
  const int tid = threadIdx.x;
  const float* xp = xin + ((size_t)bt * 64 + ch) * 4096;
  float wqv[9], wkv[9];
  #pragma unroll
  for (int i = 0; i < 9; i++) { wqv[i] = wq[ch * 9 + i]; wkv[i] = wk[ch * 9 + i]; }
  const float bqv = bq[ch], bkv = bk[ch];

  #pragma unroll
  for (int p = 0; p < 4; p++) {
    int pid = tid + p * 256;         // patch id in frame (gy*32+gx)
    int gy = pid >> 5, gx = pid & 31;
    float v[4][4];
    #pragma unroll
    for (int r = 0; r < 4; r++) {
      int yy = 2 * gy - 1 + r;
      #pragma unroll
      for (int cc = 0; cc < 4; cc++) {
        int xx = 2 * gx - 1 + cc;
        bool ok = (yy >= 0) && (yy < 64) && (xx >= 0) && (xx < 64);
        v[r][cc] = ok ? xp[yy * 64 + xx] : 0.f;
      }
    }
    unsigned short qo[4], ko[4];
    #pragma unroll
    for (int py = 0; py < 2; py++)
      #pragma unroll
      for (int px = 0; px < 2; px++) {
        float aq = bqv, ak = bkv;
        #pragma unroll
        for (int dy = 0; dy < 3; dy++)
          #pragma unroll
          for (int dx = 0; dx < 3; dx++) {
            float xv = v[py + dy][px + dx];
            aq += wqv[dy * 3 + dx] * xv;
            ak += wkv[dy * 3 + dx] * xv;
          }
        qo[py * 2 + px] = f2bf(aq);
        ko[py * 2 + px] = f2bf(ak);
      }
    size_t base = ((size_t)(b * NTOK + tf * 1024 + pid)) * DDIM + ch * 4;
    ushort4v qv = { qo[0], qo[1], qo[2], qo[3] };
    ushort4v kv = { ko[0], ko[1], ko[2], ko[3] };
    *(ushort4v*)(qt + base) = qv;
    *(ushort4v*)(kt + base) = kv;
  }
}

// ---------------- dense 3x3 conv, half the ci, row-per-WG structure -> f32 partial
// part layout: [cih][bt][co][64][64]; grid (y=64, cih=2, bt=10); thread = (co, x-quad)
__global__ __launch_bounds__(256) void conv3x3(
    const float* __restrict__ src, const float* __restrict__ wmat,
    float* __restrict__ part)
{
  const int y = blockIdx.x;     // 0..63
  const int cih = blockIdx.y;   // 0..1
  const int bt = blockIdx.z;    // 0..9
  const int t = threadIdx.x;
  const int co = t >> 2;
  const int x0 = (t & 3) * 16;

  float acc[16];
  #pragma unroll
  for (int i = 0; i < 16; i++) acc[i] = 0.f;

  #pragma unroll 1
  for (int cl = 0; cl < 32; ++cl) {
    const int ci = cih * 32 + cl;
    const float* xp = src + ((size_t)(bt * 64 + ci)) * 4096;
    const float* wp = wmat + ((size_t)co * 64 + ci) * 9;
    float w[9];
    #pragma unroll
    for (int i = 0; i < 9; i++) w[i] = wp[i];
    float vr[3][18];
    #pragma unroll
    for (int r = 0; r < 3; r++) {
      const int row = y - 1 + r;
      if (row >= 0 && row < 64) {
        const float* rp = xp + row * 64 + x0;
        #pragma unroll
        for (int q = 0; q < 4; q++) {
          f32x4 v = *(const f32x4*)(rp + q * 4);
          vr[r][q*4+1] = v[0]; vr[r][q*4+2] = v[1];
          vr[r][q*4+3] = v[2]; vr[r][q*4+4] = v[3];
        }
        vr[r][0]  = (x0 > 0)  ? rp[-1] : 0.f;
        vr[r][17] = (x0 < 48) ? rp[16] : 0.f;
      } else {
        #pragma unroll
        for (int i = 0; i < 18; i++) vr[r][i] = 0.f;
      }
    }
    #pragma unroll
    for (int r = 0; r < 3; r++)
      #pragma unroll
      for (int dx = 0; dx < 3; dx++) {
        const float wv = w[r * 3 + dx];
        #pragma unroll
        for (int i = 0; i < 16; i++) acc[i] += wv * vr[r][i + dx];
      }
  }
  float* pp = part + (((size_t)cih * 10 + bt) * 64 + co) * 4096 + y * 64 + x0;
  #pragma unroll
  for (int q = 0; q < 4; q++) {
    f32x4 ov = { acc[q*4+0], acc[q*4+1], acc[q*4+2], acc[q*4+3] };
    *(f32x4*)(pp + q * 4) = ov;
  }
}

// ---------------- V combine: sum 2 partials + bias -> bf16 tokens d-major [b][256][5120]
__global__ __launch_bounds__(256) void v_combine(
    const float* __restrict__ part, const float* __restrict__ bv,
    unsigned short* __restrict__ vt)
{
  const int co = blockIdx.x;   // 0..63
  const int bt = blockIdx.y;   // 0..9
  const int b = bt / 5, tf = bt % 5;
  const int t = threadIdx.x;
  const int y = t >> 2, xq = (t & 3) * 16;
  const float vb = bv[co];
  const float* p0 = part + (((size_t)0 * 10 + bt) * 64 + co) * 4096 + y * 64 + xq;
  const float* p1 = part + (((size_t)1 * 10 + bt) * 64 + co) * 4096 + y * 64 + xq;
  float val[16];
  #pragma unroll
  for (int q = 0; q < 4; q++) {
    f32x4 a = *(const f32x4*)(p0 + q * 4);
    f32x4 bq4 = *(const f32x4*)(p1 + q * 4);
    val[q*4+0] = a[0] + bq4[0] + vb; val[q*4+1] = a[1] + bq4[1] + vb;
    val[q*4+2] = a[2] + bq4[2] + vb; val[q*4+3] = a[3] + bq4[3] + vb;
  }
  int py = y & 1, gy = y >> 1;
  ushort8 w0, w1;
  #pragma unroll
  for (int i = 0; i < 8; i++) {
    w0[i] = f2bf(val[2 * i + 0]);   // px=0
    w1[i] = f2bf(val[2 * i + 1]);   // px=1
  }
  size_t base0 = ((size_t)(b * DDIM + co * 4 + py * 2)) * NTOK + tf * 1024 + gy * 32 + (xq >> 1);
  *(ushort8*)(vt + base0) = w0;
  *(ushort8*)(vt + base0 + NTOK) = w1;
}

// ---------------- flash attention partials: 2 i-strips/wave (32 rows), j-chunked
__global__ __launch_bounds__(256) void attn_kernel(
    const unsigned short* __restrict__ qt, const unsigned short* __restrict__ kt,
    const unsigned short* __restrict__ vt, float* __restrict__ po,
    float* __restrict__ pm, float* __restrict__ pl, int jchunk)
{
  const int b = blockIdx.z;
  const int jc = blockIdx.y;
  const int njc = gridDim.y;
  const int i0 = blockIdx.x * 128;
  const int tid = threadIdx.x;
  const int w = tid >> 6, lane = tid & 63;
  const int g = lane >> 4, c = lane & 15;

  __shared__ __align__(16) unsigned short lds_k[64 * 256];    // 32 KB [j][d] swizzled
  __shared__ __align__(16) unsigned short lds_v[256 * 64];    // 32 KB [d][j] swizzled
  __shared__ __align__(16) unsigned short lds_p[4 * 32 * 64]; // 16 KB per-wave P

  short8 qf[2][8];
  #pragma unroll
  for (int st = 0; st < 2; st++) {
    const unsigned short* qr = qt + ((size_t)(b * NTOK + i0 + w * 32 + st * 16 + c)) * DDIM + g * 8;
    #pragma unroll
    for (int kb = 0; kb < 8; kb++) qf[st][kb] = *(const short8*)(qr + kb * 32);
  }
  f32x4 o[32];
  #pragma unroll
  for (int i = 0; i < 32; i++) o[i] = (f32x4){ 0.f, 0.f, 0.f, 0.f };
  float m[2][4], l[2][4];
  #pragma unroll
  for (int st = 0; st < 2; st++)
    #pragma unroll
    for (int r = 0; r < 4; r++) { m[st][r] = -1e30f; l[st][r] = 0.f; }

  const int sr = tid >> 5, sc = tid & 31;
  const int vdr = tid >> 3, vcc = tid & 7;

  const int jbeg = jc * jchunk;
  for (int j0 = jbeg; j0 < jbeg + jchunk; j0 += 64) {
    // stage K tile [64][256]
    #pragma unroll
    for (int p = 0; p < 8; p++) {
      int row = sr + p * 8;
      short8 kv = *(const short8*)(kt + ((size_t)(b * NTOK + j0 + row)) * DDIM + sc * 8);
      *(short8*)((char*)lds_k + row * 512 + ((sc ^ (row & 7)) * 16)) = kv;
    }
    // stage V tile [256][64]
    #pragma unroll
    for (int p = 0; p < 8; p++) {
      int dd = vdr + p * 32;
      short8 vv = *(const short8*)(vt + ((size_t)(b * DDIM + dd)) * NTOK + j0 + vcc * 8);
      *(short8*)((char*)lds_v + dd * 128 + ((vcc ^ (dd & 7)) * 16)) = vv;
    }
    __syncthreads();

    // S = Q*K^T for both strips; one kf read feeds 2 MFMAs
    f32x4 s0[4], s1[4];
    #pragma unroll
    for (int js = 0; js < 4; js++) {
      s0[js] = (f32x4){ 0.f, 0.f, 0.f, 0.f };
      s1[js] = (f32x4){ 0.f, 0.f, 0.f, 0.f };
      int row = js * 16 + c;
      int sw = row & 7;
      #pragma unroll
      for (int kb = 0; kb < 8; kb++) {
        short8 kf = *(const short8*)((char*)lds_k + row * 512 + (((kb * 4 + g) ^ sw) * 16));
        s0[js] = __builtin_amdgcn_mfma_f32_16x16x32_bf16(qf[0][kb], kf, s0[js], 0, 0, 0);
        s1[js] = __builtin_amdgcn_mfma_f32_16x16x32_bf16(qf[1][kb], kf, s1[js], 0, 0, 0);
      }
    }
    // online softmax per strip
    char* pb = (char*)lds_p + w * 4096;
    #pragma unroll
    for (int st = 0; st < 2; st++) {
      float pvv[4][4], alpha[4];
      #pragma unroll
      for (int r = 0; r < 4; r++) {
        float a0 = st ? s1[0][r] : s0[0][r];
        float a1 = st ? s1[1][r] : s0[1][r];
        float a2 = st ? s1[2][r] : s0[2][r];
        float a3 = st ? s1[3][r] : s0[3][r];
        float mx = fmaxf(fmaxf(a0, a1), fmaxf(a2, a3)) * 0.0625f;
        #pragma unroll
        for (int off = 1; off < 16; off <<= 1) mx = fmaxf(mx, __shfl_xor(mx, off));
        float mn = fmaxf(m[st][r], mx);
        alpha[r] = __expf(m[st][r] - mn);
        float p0 = __expf(a0 * 0.0625f - mn);
        float p1 = __expf(a1 * 0.0625f - mn);
        float p2 = __expf(a2 * 0.0625f - mn);
        float p3 = __expf(a3 * 0.0625f - mn);
        pvv[0][r] = p0; pvv[1][r] = p1; pvv[2][r] = p2; pvv[3][r] = p3;
        float sum = p0 + p1 + p2 + p3;
        #pragma unroll
        for (int off = 1; off < 16; off <<= 1) sum += __shfl_xor(sum, off);
        l[st][r] = l[st][r] * alpha[r] + sum;
        m[st][r] = mn;
      }
      f32x4 av = { alpha[0], alpha[1], alpha[2], alpha[3] };
      #pragma unroll
      for (int ds = 0; ds < 16; ds++) o[st * 16 + ds] *= av;
      #pragma unroll
      for (int js = 0; js < 4; js++)
        #pragma unroll
        for (int r = 0; r < 4; r++) {
          int row = st * 16 + 4 * g + r;
          int slot = (js * 2 + (c >> 3)) ^ (row & 7);
          *(unsigned short*)(pb + row * 128 + slot * 16 + (c & 7) * 2) = f2bf(pvv[js][r]);
        }
    }
    short8 pf[2][2];
    #pragma unroll
    for (int st = 0; st < 2; st++)
      #pragma unroll
      for (int k2 = 0; k2 < 2; k2++)
        pf[st][k2] = *(short8*)(pb + (st * 16 + c) * 128 + (((k2 * 4 + g) ^ (c & 7)) * 16));
    // O += P*V for both strips; one vf read feeds 2 MFMAs
    #pragma unroll
    for (int ds = 0; ds < 16; ds++) {
      int vrow = ds * 16 + c;
      int sw = c & 7;
      #pragma unroll
      for (int k2 = 0; k2 < 2; k2++) {
        short8 vf = *(const short8*)((char*)lds_v + vrow * 128 + (((k2 * 4 + g) ^ sw) * 16));
        o[ds]      = __builtin_amdgcn_mfma_f32_16x16x32_bf16(pf[0][k2], vf, o[ds], 0, 0, 0);
        o[16 + ds] = __builtin_amdgcn_mfma_f32_16x16x32_bf16(pf[1][k2], vf, o[16 + ds], 0, 0, 0);
      }
    }
    __syncthreads();
  }
  // epilogue: unnormalized partials
  #pragma unroll
  for (int st = 0; st < 2; st++) {
    const size_t rbase = ((size_t)(b * njc + jc)) * NTOK + i0 + w * 32 + st * 16;
    #pragma unroll
    for (int ds = 0; ds < 16; ds++)
      #pragma unroll
      for (int r = 0; r < 4; r++)
        po[(rbase + 4 * g + r) * DDIM + ds * 16 + c] = o[st * 16 + ds][r];
    if (c == 0) {
      #pragma unroll
      for (int r = 0; r < 4; r++) {
        pm[rbase + 4 * g + r] = m[st][r];
        pl[rbase + 4 * g + r] = l[st][r];
      }
    }
  }
}

// ---------------- attn combine: online LSE merge of njc partials, fold into feat
__global__ __launch_bounds__(256) void attn_combine(
    const float* __restrict__ po, const float* __restrict__ pm,
    const float* __restrict__ pl, float* __restrict__ feat, int njc)
{
  const int b = blockIdx.y;
  const int i0 = blockIdx.x * 64;
  const int t = threadIdx.x;
  const int row = t >> 2, dq = (t & 3) * 64;
  const int i = i0 + row;

  float M = -1e30f, L = 0.f;
  f32x4 acc[16];
  #pragma unroll
  for (int q = 0; q < 16; q++) acc[q] = (f32x4){ 0.f, 0.f, 0.f, 0.f };

  #pragma unroll 1
  for (int jc = 0; jc < njc; jc++) {
    const size_t rb = ((size_t)(b * njc + jc)) * NTOK + i;
    float mj = pm[rb], lj = pl[rb];
    float mn = fmaxf(M, mj);
    float so = __expf(M - mn), sn = __expf(mj - mn);
    const float* pp = po + rb * DDIM + dq;
    #pragma unroll
    for (int q = 0; q < 16; q++) {
      f32x4 v = *(const f32x4*)(pp + q * 4);
      acc[q] = acc[q] * so + v * sn;
    }
    L = L * so + lj * sn;
    M = mn;
  }
  const float inv = 1.f / L;
  const int tf = i >> 10, jn = i & 1023;
  const int gy = jn >> 5, gx = jn & 31;
  const size_t fb = ((size_t)((b * 5 + tf) * 64)) * 4096 + (2 * gy) * 64 + 2 * gx;
  #pragma unroll
  for (int q = 0; q < 16; q++) {
    f32x4 a = acc[q] * inv;
    int ch = (dq + q * 4) >> 2;
    size_t base = fb + (size_t)ch * 4096;
    feat[base] = a[0]; feat[base + 1] = a[1];
    feat[base + 64] = a[2]; feat[base + 65] = a[3];
  }
}

// ---------------- out combine: sum 2 partials + bias + residual -> out (f32)
__global__ __launch_bounds__(256) void out_combine(
    const float* __restrict__ part, const float* __restrict__ bc,
    const float* __restrict__ xin, float* __restrict__ out)
{
  const int co = blockIdx.x;   // 0..63
  const int bt = blockIdx.y;   // 0..9
  const int t = threadIdx.x;
  const int y = t >> 2, xq = (t & 3) * 16;
  const float bcv = bc[co];
  const size_t obase = ((size_t)bt * 64 + co) * 4096 + y * 64 + xq;
  const float* p0 = part + (((size_t)0 * 10 + bt) * 64 + co) * 4096 + y * 64 + xq;
  const float* p1 = part + (((size_t)1 * 10 + bt) * 64 + co) * 4096 + y * 64 + xq;
  #pragma unroll
  for (int q = 0; q < 4; q++) {
    f32x4 a = *(const f32x4*)(p0 + q * 4);
    f32x4 bb = *(const f32x4*)(p1 + q * 4);
    f32x4 xr = *(const f32x4*)(xin + obase + q * 4);
    f32x4 ov;
    ov[0] = a[0] + bb[0] + bcv + xr[0];
    ov[1] = a[1] + bb[1] + bcv + xr[1];
    ov[2] = a[2] + bb[2] + bcv + xr[2];
    ov[3] = a[3] + bb[3] + bcv + xr[3];
    *(f32x4*)(out + obase + q * 4) = ov;
  }
}

extern "C" void kernel_launch(void* const* d_in, const int* in_sizes, int n_in,
                              void* d_out, int out_size, void* d_ws, size_t ws_size,
                              hipStream_t stream) {
  const float* x  = (const float*)d_in[0];
  const float* wq = (const float*)d_in[1];
  const float* bq = (const float*)d_in[2];
  const float* wk = (const float*)d_in[3];
  const float* bk = (const float*)d_in[4];
  const float* wv = (const float*)d_in[5];
  const float* bv = (const float*)d_in[6];
  const float* wc = (const float*)d_in[7];
  const float* bc = (const float*)d_in[8];
  float* out = (float*)d_out;

  char* ws = (char*)d_ws;
  unsigned short* qt = (unsigned short*)(ws);              //  5,242,880 B
  unsigned short* kt = (unsigned short*)(ws + 5242880);    //  5,242,880 B
  unsigned short* vt = (unsigned short*)(ws + 10485760);   //  5,242,880 B
  float*          ft = (float*)(ws + 15728640);            // 10,485,760 B
  const size_t big_off = 26214400;
  float*          big = (float*)(ws + big_off);            // conv partials / attn po

  // choose j-split by available workspace: po = 2*njc*5120*256*4 bytes
  int njc = 10;
  size_t po_bytes = (size_t)2 * njc * NTOK * DDIM * 4;
  if (big_off + po_bytes + 2 * (size_t)2 * njc * NTOK * 4 > ws_size) {
    njc = 4;
    po_bytes = (size_t)2 * njc * NTOK * DDIM * 4;
  }
  float* pm = (float*)(ws + big_off + po_bytes);
  float* pl = pm + (size_t)2 * njc * NTOK;
  const int jchunk = NTOK / njc;

  qk_gen      <<<dim3(64, 10), 256, 0, stream>>>(x, wq, bq, wk, bk, qt, kt);
  conv3x3     <<<dim3(64, 2, 10), 256, 0, stream>>>(x, wv, big);
  v_combine   <<<dim3(64, 10), 256, 0, stream>>>(big, bv, vt);
  attn_kernel <<<dim3(40, njc, 2), 256, 0, stream>>>(qt, kt, vt, big, pm, pl, jchunk);
  attn_combine<<<dim3(80, 2), 256, 0, stream>>>(big, pm, pl, ft, njc);
  conv3x3     <<<dim3(64, 2, 10), 256, 0, stream>>>(ft, wc, big);
  out_combine <<<dim3(64, 10), 256, 0, stream>>>(big, bc, x, out);
}

// Round 4
// 295.409 us; speedup vs baseline: 3.5194x; 1.9758x over previous
//
#include <hip/hip_runtime.h>
#include <hip/hip_bf16.h>

typedef __attribute__((ext_vector_type(8))) short short8;
typedef __attribute__((ext_vector_type(8))) unsigned short ushort8;
typedef __attribute__((ext_vector_type(4))) unsigned short ushort4v;
typedef __attribute__((ext_vector_type(4))) float f32x4;

#define NTOK 5120
#define DDIM 256

__device__ __forceinline__ unsigned short f2bf(float f) {
  union { float f; unsigned int u; } x; x.f = f;
  unsigned int r = x.u + 0x7FFFu + ((x.u >> 16) & 1u);
  return (unsigned short)(r >> 16);
}

// ---------------- Kernel 1: depthwise conv Q,K + unfold -> token-major bf16 [b][5120][256]
__global__ __launch_bounds__(256) void qk_gen(
    const float* __restrict__ xin, const float* __restrict__ wq,
    const float* __restrict__ bq, const float* __restrict__ wk,
    const float* __restrict__ bk, unsigned short* __restrict__ qt,
    unsigned short* __restrict__ kt)
{
  const int ch = blockIdx.x;   // 0..63
  const int bt = blockIdx.y;   // 0..9
  const int b = bt / 5, tf = bt % 5;
  const int tid = threadIdx.x;
  const float* xp = xin + ((size_t)bt * 64 + ch) * 4096;
  float wqv[9], wkv[9];
  #pragma unroll
  for (int i = 0; i < 9; i++) { wqv[i] = wq[ch * 9 + i]; wkv[i] = wk[ch * 9 + i]; }
  const float bqv = bq[ch], bkv = bk[ch];

  #pragma unroll
  for (int p = 0; p < 4; p++) {
    int pid = tid + p * 256;         // patch id in frame (gy*32+gx)
    int gy = pid >> 5, gx = pid & 31;
    float v[4][4];
    #pragma unroll
    for (int r = 0; r < 4; r++) {
      int yy = 2 * gy - 1 + r;
      #pragma unroll
      for (int cc = 0; cc < 4; cc++) {
        int xx = 2 * gx - 1 + cc;
        bool ok = (yy >= 0) && (yy < 64) && (xx >= 0) && (xx < 64);
        v[r][cc] = ok ? xp[yy * 64 + xx] : 0.f;
      }
    }
    unsigned short qo[4], ko[4];
    #pragma unroll
    for (int py = 0; py < 2; py++)
      #pragma unroll
      for (int px = 0; px < 2; px++) {
        float aq = bqv, ak = bkv;
        #pragma unroll
        for (int dy = 0; dy < 3; dy++)
          #pragma unroll
          for (int dx = 0; dx < 3; dx++) {
            float xv = v[py + dy][px + dx];
            aq += wqv[dy * 3 + dx] * xv;
            ak += wkv[dy * 3 + dx] * xv;
          }
        qo[py * 2 + px] = f2bf(aq);
        ko[py * 2 + px] = f2bf(ak);
      }
    size_t base = ((size_t)(b * NTOK + tf * 1024 + pid)) * DDIM + ch * 4;
    ushort4v qv = { qo[0], qo[1], qo[2], qo[3] };
    ushort4v kv = { ko[0], ko[1], ko[2], ko[3] };
    *(ushort4v*)(qt + base) = qv;
    *(ushort4v*)(kt + base) = kv;
  }
}

// ---------------- weight transform: wv/wc [co][ci][9] f32 -> [tap][co][ci] bf16
__global__ __launch_bounds__(256) void wt_gen(
    const float* __restrict__ w0, const float* __restrict__ w1,
    unsigned short* __restrict__ o0, unsigned short* __restrict__ o1)
{
  const int tap = blockIdx.x;            // 0..8
  const float* src = blockIdx.y ? w1 : w0;
  unsigned short* dst = blockIdx.y ? o1 : o0;
  const int t = threadIdx.x;
  #pragma unroll
  for (int i = 0; i < 16; i++) {
    int oi = t + i * 256;                // co*64+ci
    dst[tap * 4096 + oi] = f2bf(src[(size_t)oi * 9 + tap]);
  }
}

// ---------------- implicit-GEMM MFMA conv: 3x3 SAME, 64ci -> 64co, bf16 MFMA, f32 out (no bias)
// grid (strip=16, bt=10); WG = 4 output rows (one per wave) x 64 cols
__global__ __launch_bounds__(256) void conv_mfma(
    const float* __restrict__ src,          // [bt][64][64][64] f32
    const unsigned short* __restrict__ wt,  // [9][64][64] bf16
    float* __restrict__ dst)                // [bt][64][64][64] f32
{
  const int strip = blockIdx.x;  // 0..15
  const int bt = blockIdx.y;     // 0..9
  const int y0 = strip * 4;
  const int tid = threadIdx.x;
  const int sw = tid >> 6, lane = tid & 63;
  const int g = lane >> 4, c = lane & 15;

  __shared__ __align__(16) unsigned short lds_in[6 * 66 * 64]; // [row][lcol][ci], slot^=(lcol&7)
  __shared__ __align__(16) unsigned short lds_w[64 * 64];      // [co][ci], slot^=(co&7)

  // ---- stage input (wave sw stages ci in [sw*16, sw*16+16))
  {
    const int rr0 = lane >> 4;        // 0..3
    const int cb = lane & 15;         // col block (4 cols each)
    #pragma unroll
    for (int pass = 0; pass < 2; ++pass) {
      int rr = pass * 4 + rr0;        // 0..7
      if (rr < 6) {
        int row = y0 - 1 + rr;
        bool rok = (row >= 0) && (row < 64);
        #pragma unroll 4
        for (int cii = 0; cii < 16; ++cii) {
          int ci = sw * 16 + cii;
          f32x4 v = { 0.f, 0.f, 0.f, 0.f };
          if (rok) v = *(const f32x4*)(src + ((size_t)(bt * 64 + ci)) * 4096 + row * 64 + cb * 4);
          char* base = (char*)lds_in + (rr * 66) * 128 + (ci & 7) * 2;
          #pragma unroll
          for (int q = 0; q < 4; ++q) {
            int lcol = cb * 4 + q + 1;
            *(unsigned short*)(base + lcol * 128 + (((ci >> 3) ^ (lcol & 7)) * 16)) = f2bf(v[q]);
          }
          if (cb == 0)
            *(unsigned short*)(base + (((ci >> 3) ^ 0) * 16)) = 0;          // lcol 0
          if (cb == 15)
            *(unsigned short*)(base + 65 * 128 + (((ci >> 3) ^ 1) * 16)) = 0; // lcol 65
        }
      }
    }
  }

  f32x4 acc[4][4];
  #pragma unroll
  for (int ct = 0; ct < 4; ct++)
    #pragma unroll
    for (int xt = 0; xt < 4; xt++) acc[ct][xt] = (f32x4){ 0.f, 0.f, 0.f, 0.f };

  #pragma unroll 1
  for (int tap = 0; tap < 9; ++tap) {
    __syncthreads();   // prev-tap readers done (1st iter: input staging fence pairs w/ next sync)
    {
      const unsigned short* wp = wt + tap * 4096;
      #pragma unroll
      for (int h = 0; h < 2; ++h) {
        int el = h * 2048 + tid * 8;
        int co = el >> 6, sl = (el & 63) >> 3;
        short8 wv8 = *(const short8*)(wp + el);
        *(short8*)((char*)lds_w + co * 128 + ((sl ^ (co & 7)) * 16)) = wv8;
      }
    }
    __syncthreads();
    const int dy = tap / 3 - 1, dx = tap % 3 - 1;
    const int rowp = sw + 1 + dy;       // LDS row for this wave's output row
    #pragma unroll
    for (int kblk = 0; kblk < 2; ++kblk) {
      short8 af[4], bf[4];
      #pragma unroll
      for (int ct = 0; ct < 4; ++ct)
        af[ct] = *(const short8*)((char*)lds_w + (ct * 16 + c) * 128 + ((((kblk << 2) + g) ^ (c & 7)) * 16));
      #pragma unroll
      for (int xt = 0; xt < 4; ++xt) {
        int lcol = xt * 16 + c + dx + 1;
        bf[xt] = *(const short8*)((char*)lds_in + (rowp * 66 + lcol) * 128 + ((((kblk << 2) + g) ^ (lcol & 7)) * 16));
      }
      #pragma unroll
      for (int ct = 0; ct < 4; ++ct)
        #pragma unroll
        for (int xt = 0; xt < 4; ++xt)
          acc[ct][xt] = __builtin_amdgcn_mfma_f32_16x16x32_bf16(af[ct], bf[xt], acc[ct][xt], 0, 0, 0);
    }
  }

  // ---- epilogue: lane holds C[co=ct*16+g*4+r][x=xt*16+c] for row y0+sw
  const int y = y0 + sw;
  float* dp = dst + ((size_t)bt * 64) * 4096 + y * 64;
  #pragma unroll
  for (int ct = 0; ct < 4; ++ct)
    #pragma unroll
    for (int xt = 0; xt < 4; ++xt)
      #pragma unroll
      for (int r = 0; r < 4; ++r) {
        int co = ct * 16 + g * 4 + r;
        dp[(size_t)co * 4096 + xt * 16 + c] = acc[ct][xt][r];
      }
}

// ---------------- V combine: partial + bias -> bf16 tokens d-major [b][256][5120]
__global__ __launch_bounds__(256) void v_combine(
    const float* __restrict__ part, const float* __restrict__ bv,
    unsigned short* __restrict__ vt)
{
  const int co = blockIdx.x;   // 0..63
  const int bt = blockIdx.y;   // 0..9
  const int b = bt / 5, tf = bt % 5;
  const int t = threadIdx.x;
  const int y = t >> 2, xq = (t & 3) * 16;
  const float vb = bv[co];
  const float* p0 = part + ((size_t)bt * 64 + co) * 4096 + y * 64 + xq;
  float val[16];
  #pragma unroll
  for (int q = 0; q < 4; q++) {
    f32x4 a = *(const f32x4*)(p0 + q * 4);
    val[q*4+0] = a[0] + vb; val[q*4+1] = a[1] + vb;
    val[q*4+2] = a[2] + vb; val[q*4+3] = a[3] + vb;
  }
  int py = y & 1, gy = y >> 1;
  ushort8 w0, w1;
  #pragma unroll
  for (int i = 0; i < 8; i++) {
    w0[i] = f2bf(val[2 * i + 0]);   // px=0
    w1[i] = f2bf(val[2 * i + 1]);   // px=1
  }
  size_t base0 = ((size_t)(b * DDIM + co * 4 + py * 2)) * NTOK + tf * 1024 + gy * 32 + (xq >> 1);
  *(ushort8*)(vt + base0) = w0;
  *(ushort8*)(vt + base0 + NTOK) = w1;
}

// ---------------- flash attention partials: 2 i-strips/wave (32 rows), j-chunked
__global__ __launch_bounds__(256) void attn_kernel(
    const unsigned short* __restrict__ qt, const unsigned short* __restrict__ kt,
    const unsigned short* __restrict__ vt, float* __restrict__ po,
    float* __restrict__ pm, float* __restrict__ pl, int jchunk)
{
  const int b = blockIdx.z;
  const int jc = blockIdx.y;
  const int njc = gridDim.y;
  const int i0 = blockIdx.x * 128;
  const int tid = threadIdx.x;
  const int w = tid >> 6, lane = tid & 63;
  const int g = lane >> 4, c = lane & 15;

  __shared__ __align__(16) unsigned short lds_k[64 * 256];    // 32 KB [j][d] swizzled
  __shared__ __align__(16) unsigned short lds_v[256 * 64];    // 32 KB [d][j] swizzled
  __shared__ __align__(16) unsigned short lds_p[4 * 32 * 64]; // 16 KB per-wave P

  short8 qf[2][8];
  #pragma unroll
  for (int st = 0; st < 2; st++) {
    const unsigned short* qr = qt + ((size_t)(b * NTOK + i0 + w * 32 + st * 16 + c)) * DDIM + g * 8;
    #pragma unroll
    for (int kb = 0; kb < 8; kb++) qf[st][kb] = *(const short8*)(qr + kb * 32);
  }
  f32x4 o[32];
  #pragma unroll
  for (int i = 0; i < 32; i++) o[i] = (f32x4){ 0.f, 0.f, 0.f, 0.f };
  float m[2][4], l[2][4];
  #pragma unroll
  for (int st = 0; st < 2; st++)
    #pragma unroll
    for (int r = 0; r < 4; r++) { m[st][r] = -1e30f; l[st][r] = 0.f; }

  const int sr = tid >> 5, sc = tid & 31;
  const int vdr = tid >> 3, vcc = tid & 7;

  const int jbeg = jc * jchunk;
  for (int j0 = jbeg; j0 < jbeg + jchunk; j0 += 64) {
    #pragma unroll
    for (int p = 0; p < 8; p++) {
      int row = sr + p * 8;
      short8 kv = *(const short8*)(kt + ((size_t)(b * NTOK + j0 + row)) * DDIM + sc * 8);
      *(short8*)((char*)lds_k + row * 512 + ((sc ^ (row & 7)) * 16)) = kv;
    }
    #pragma unroll
    for (int p = 0; p < 8; p++) {
      int dd = vdr + p * 32;
      short8 vv = *(const short8*)(vt + ((size_t)(b * DDIM + dd)) * NTOK + j0 + vcc * 8);
      *(short8*)((char*)lds_v + dd * 128 + ((vcc ^ (dd & 7)) * 16)) = vv;
    }
    __syncthreads();

    f32x4 s0[4], s1[4];
    #pragma unroll
    for (int js = 0; js < 4; js++) {
      s0[js] = (f32x4){ 0.f, 0.f, 0.f, 0.f };
      s1[js] = (f32x4){ 0.f, 0.f, 0.f, 0.f };
      int row = js * 16 + c;
      int sw2 = row & 7;
      #pragma unroll
      for (int kb = 0; kb < 8; kb++) {
        short8 kf = *(const short8*)((char*)lds_k + row * 512 + (((kb * 4 + g) ^ sw2) * 16));
        s0[js] = __builtin_amdgcn_mfma_f32_16x16x32_bf16(qf[0][kb], kf, s0[js], 0, 0, 0);
        s1[js] = __builtin_amdgcn_mfma_f32_16x16x32_bf16(qf[1][kb], kf, s1[js], 0, 0, 0);
      }
    }
    char* pb = (char*)lds_p + w * 4096;
    #pragma unroll
    for (int st = 0; st < 2; st++) {
      float pvv[4][4], alpha[4];
      #pragma unroll
      for (int r = 0; r < 4; r++) {
        float a0 = st ? s1[0][r] : s0[0][r];
        float a1 = st ? s1[1][r] : s0[1][r];
        float a2 = st ? s1[2][r] : s0[2][r];
        float a3 = st ? s1[3][r] : s0[3][r];
        float mx = fmaxf(fmaxf(a0, a1), fmaxf(a2, a3)) * 0.0625f;
        #pragma unroll
        for (int off = 1; off < 16; off <<= 1) mx = fmaxf(mx, __shfl_xor(mx, off));
        float mn = fmaxf(m[st][r], mx);
        alpha[r] = __expf(m[st][r] - mn);
        float p0 = __expf(a0 * 0.0625f - mn);
        float p1 = __expf(a1 * 0.0625f - mn);
        float p2 = __expf(a2 * 0.0625f - mn);
        float p3 = __expf(a3 * 0.0625f - mn);
        pvv[0][r] = p0; pvv[1][r] = p1; pvv[2][r] = p2; pvv[3][r] = p3;
        float sum = p0 + p1 + p2 + p3;
        #pragma unroll
        for (int off = 1; off < 16; off <<= 1) sum += __shfl_xor(sum, off);
        l[st][r] = l[st][r] * alpha[r] + sum;
        m[st][r] = mn;
      }
      f32x4 av = { alpha[0], alpha[1], alpha[2], alpha[3] };
      #pragma unroll
      for (int ds = 0; ds < 16; ds++) o[st * 16 + ds] *= av;
      #pragma unroll
      for (int js = 0; js < 4; js++)
        #pragma unroll
        for (int r = 0; r < 4; r++) {
          int row = st * 16 + 4 * g + r;
          int slot = (js * 2 + (c >> 3)) ^ (row & 7);
          *(unsigned short*)(pb + row * 128 + slot * 16 + (c & 7) * 2) = f2bf(pvv[js][r]);
        }
    }
    short8 pf[2][2];
    #pragma unroll
    for (int st = 0; st < 2; st++)
      #pragma unroll
      for (int k2 = 0; k2 < 2; k2++)
        pf[st][k2] = *(short8*)(pb + (st * 16 + c) * 128 + (((k2 * 4 + g) ^ (c & 7)) * 16));
    #pragma unroll
    for (int ds = 0; ds < 16; ds++) {
      int vrow = ds * 16 + c;
      int sw2 = c & 7;
      #pragma unroll
      for (int k2 = 0; k2 < 2; k2++) {
        short8 vf = *(const short8*)((char*)lds_v + vrow * 128 + (((k2 * 4 + g) ^ sw2) * 16));
        o[ds]      = __builtin_amdgcn_mfma_f32_16x16x32_bf16(pf[0][k2], vf, o[ds], 0, 0, 0);
        o[16 + ds] = __builtin_amdgcn_mfma_f32_16x16x32_bf16(pf[1][k2], vf, o[16 + ds], 0, 0, 0);
      }
    }
    __syncthreads();
  }
  #pragma unroll
  for (int st = 0; st < 2; st++) {
    const size_t rbase = ((size_t)(b * njc + jc)) * NTOK + i0 + w * 32 + st * 16;
    #pragma unroll
    for (int ds = 0; ds < 16; ds++)
      #pragma unroll
      for (int r = 0; r < 4; r++)
        po[(rbase + 4 * g + r) * DDIM + ds * 16 + c] = o[st * 16 + ds][r];
    if (c == 0) {
      #pragma unroll
      for (int r = 0; r < 4; r++) {
        pm[rbase + 4 * g + r] = m[st][r];
        pl[rbase + 4 * g + r] = l[st][r];
      }
    }
  }
}

// ---------------- attn combine: online LSE merge of njc partials, fold into feat
__global__ __launch_bounds__(256) void attn_combine(
    const float* __restrict__ po, const float* __restrict__ pm,
    const float* __restrict__ pl, float* __restrict__ feat, int njc)
{
  const int b = blockIdx.y;
  const int i0 = blockIdx.x * 64;
  const int t = threadIdx.x;
  const int row = t >> 2, dq = (t & 3) * 64;
  const int i = i0 + row;

  float M = -1e30f, L = 0.f;
  f32x4 acc[16];
  #pragma unroll
  for (int q = 0; q < 16; q++) acc[q] = (f32x4){ 0.f, 0.f, 0.f, 0.f };

  #pragma unroll 1
  for (int jc = 0; jc < njc; jc++) {
    const size_t rb = ((size_t)(b * njc + jc)) * NTOK + i;
    float mj = pm[rb], lj = pl[rb];
    float mn = fmaxf(M, mj);
    float so = __expf(M - mn), sn = __expf(mj - mn);
    const float* pp = po + rb * DDIM + dq;
    #pragma unroll
    for (int q = 0; q < 16; q++) {
      f32x4 v = *(const f32x4*)(pp + q * 4);
      acc[q] = acc[q] * so + v * sn;
    }
    L = L * so + lj * sn;
    M = mn;
  }
  const float inv = 1.f / L;
  const int tf = i >> 10, jn = i & 1023;
  const int gy = jn >> 5, gx = jn & 31;
  const size_t fb = ((size_t)((b * 5 + tf) * 64)) * 4096 + (2 * gy) * 64 + 2 * gx;
  #pragma unroll
  for (int q = 0; q < 16; q++) {
    f32x4 a = acc[q] * inv;
    int ch = (dq + q * 4) >> 2;
    size_t base = fb + (size_t)ch * 4096;
    feat[base] = a[0]; feat[base + 1] = a[1];
    feat[base + 64] = a[2]; feat[base + 65] = a[3];
  }
}

// ---------------- out combine: partial + bias + residual -> out (f32)
__global__ __launch_bounds__(256) void out_combine(
    const float* __restrict__ part, const float* __restrict__ bc,
    const float* __restrict__ xin, float* __restrict__ out)
{
  const int co = blockIdx.x;   // 0..63
  const int bt = blockIdx.y;   // 0..9
  const int t = threadIdx.x;
  const int y = t >> 2, xq = (t & 3) * 16;
  const float bcv = bc[co];
  const size_t obase = ((size_t)bt * 64 + co) * 4096 + y * 64 + xq;
  const float* p0 = part + obase;
  #pragma unroll
  for (int q = 0; q < 4; q++) {
    f32x4 a = *(const f32x4*)(p0 + q * 4);
    f32x4 xr = *(const f32x4*)(xin + obase + q * 4);
    f32x4 ov;
    ov[0] = a[0] + bcv + xr[0];
    ov[1] = a[1] + bcv + xr[1];
    ov[2] = a[2] + bcv + xr[2];
    ov[3] = a[3] + bcv + xr[3];
    *(f32x4*)(out + obase + q * 4) = ov;
  }
}

extern "C" void kernel_launch(void* const* d_in, const int* in_sizes, int n_in,
                              void* d_out, int out_size, void* d_ws, size_t ws_size,
                              hipStream_t stream) {
  const float* x  = (const float*)d_in[0];
  const float* wq = (const float*)d_in[1];
  const float* bq = (const float*)d_in[2];
  const float* wk = (const float*)d_in[3];
  const float* bk = (const float*)d_in[4];
  const float* wv = (const float*)d_in[5];
  const float* bv = (const float*)d_in[6];
  const float* wc = (const float*)d_in[7];
  const float* bc = (const float*)d_in[8];
  float* out = (float*)d_out;

  char* ws = (char*)d_ws;
  unsigned short* qt = (unsigned short*)(ws);              //  5,242,880 B
  unsigned short* kt = (unsigned short*)(ws + 5242880);    //  5,242,880 B
  unsigned short* vt = (unsigned short*)(ws + 10485760);   //  5,242,880 B
  float*          ft = (float*)(ws + 15728640);            // 10,485,760 B
  unsigned short* wtv = (unsigned short*)(ws + 26214400);  //     73,728 B
  unsigned short* wtc = (unsigned short*)(ws + 26288128);  //     73,728 B
  const size_t big_off = 26361856;
  float*          big = (float*)(ws + big_off);            // conv partial / attn po

  int njc = 10;
  size_t po_bytes = (size_t)2 * njc * NTOK * DDIM * 4;
  if (big_off + po_bytes + 2 * (size_t)2 * njc * NTOK * 4 > ws_size) {
    njc = 4;
    po_bytes = (size_t)2 * njc * NTOK * DDIM * 4;
  }
  float* pm = (float*)(ws + big_off + po_bytes);
  float* pl = pm + (size_t)2 * njc * NTOK;
  const int jchunk = NTOK / njc;

  wt_gen      <<<dim3(9, 2), 256, 0, stream>>>(wv, wc, wtv, wtc);
  qk_gen      <<<dim3(64, 10), 256, 0, stream>>>(x, wq, bq, wk, bk, qt, kt);
  conv_mfma   <<<dim3(16, 10), 256, 0, stream>>>(x, wtv, big);
  v_combine   <<<dim3(64, 10), 256, 0, stream>>>(big, bv, vt);
  attn_kernel <<<dim3(40, njc, 2), 256, 0, stream>>>(qt, kt, vt, big, pm, pl, jchunk);
  attn_combine<<<dim3(80, 2), 256, 0, stream>>>(big, pm, pl, ft, njc);
  conv_mfma   <<<dim3(16, 10), 256, 0, stream>>>(ft, wtc, big);
  out_combine <<<dim3(64, 10), 256, 0, stream>>>(big, bc, x, out);
}